// Round 14
// baseline (209.626 us; speedup 1.0000x reference)
//
#include <hip/hip_runtime.h>
#include <math.h>

#define DIM_    128
#define QH_     16
#define KVH_    4
#define WIN_    512
#define BATCH_  4
#define SEQ_    2048
#define QKV_LD  3072

// Padded workspace strides (kept from R9 — harmless).
#define QB_LD   3136   // qkvb rows (logical 3072)
#define VG_LD   2112   // vg rows   (logical 2048)
#define AH_LD   2112   // ah rows   (logical 2048)
#define WP_LD   2112   // wpth rows (logical 2048)

#define NX   (BATCH_*SEQ_*DIM_)   // 1048576
#define NWQ  (DIM_*QKV_LD)        // 393216

typedef __attribute__((ext_vector_type(8))) short short8;
typedef __attribute__((ext_vector_type(4))) float f32x4;
typedef unsigned short u16;
typedef unsigned int u32;

__device__ __forceinline__ u16 f2bf(float f) {
    u32 u = __float_as_uint(f);
    u += 0x7fff + ((u >> 16) & 1);
    return (u16)(u >> 16);
}
__device__ __forceinline__ float bf2f(u16 u) {
    return __uint_as_float(((u32)u) << 16);
}
// pack 2 f32 -> 2 bf16 (RNE), single VALU instr (no builtin on gfx950)
__device__ __forceinline__ u32 pkbf(float a, float b) {
    u32 r;
    __asm__("v_cvt_pk_bf16_f32 %0, %1, %2" : "=v"(r) : "v"(a), "v"(b));
    return r;
}
#define MFMA16 __builtin_amdgcn_mfma_f32_16x16x32_bf16

#if __has_builtin(__builtin_amdgcn_exp2f)
#define EXP2F __builtin_amdgcn_exp2f
#else
#define EXP2F exp2f
#endif

__device__ __forceinline__ void gload_lds16(const u16* g, u16* l) {
    __builtin_amdgcn_global_load_lds(
        (const __attribute__((address_space(1))) unsigned int*)(const void*)g,
        (__attribute__((address_space(3))) unsigned int*)(void*)l, 16, 0, 0);
}

// ---------- prep: xcvt + wtrans fused (unchanged) --------------------------
__global__ __launch_bounds__(256) void prep(
    const float* __restrict__ x, const float* __restrict__ Wqkv,
    const float* __restrict__ Wproj,
    u16* __restrict__ xh, u16* __restrict__ wth, u16* __restrict__ wpth)
{
    if (blockIdx.x < 1024) {
        const size_t t = (size_t)blockIdx.x * 256 + threadIdx.x;
        float4 v = *(const float4*)(x + 4 * t);
        ushort4 o;
        o.x = f2bf(v.x); o.y = f2bf(v.y); o.z = f2bf(v.z); o.w = f2bf(v.w);
        *(ushort4*)(xh + 4 * t) = o;
        return;
    }
    __shared__ float T[32][33];
    int tile = blockIdx.x - 1024;
    const float* src; u16* dst; int N, ldo;
    if (tile < 384) { src = Wqkv;  dst = wth;  N = 3072; ldo = 128; }
    else { tile -= 384; src = Wproj; dst = wpth; N = 128; ldo = WP_LD; }
    const int ntile = N >> 5;
    const int k0 = (tile / ntile) << 5, n0 = (tile % ntile) << 5;
    const int tx = threadIdx.x & 31, ty = threadIdx.x >> 5;
    #pragma unroll
    for (int i = 0; i < 4; ++i)
        T[ty + 8 * i][tx] = src[(size_t)(k0 + ty + 8 * i) * N + n0 + tx];
    __syncthreads();
    #pragma unroll
    for (int i = 0; i < 4; ++i)
        dst[(size_t)(n0 + ty + 8 * i) * ldo + k0 + tx] = f2bf(T[tx][ty + 8 * i]);
}

// ---------- GEMM1 v4: LDS-staged store epilogue (unchanged from R12) -------
__global__ __launch_bounds__(256) void gemm1_mfma(
    const u16* __restrict__ xh, const u16* __restrict__ wth,
    u16* __restrict__ qkvb, u16* __restrict__ vg)
{
    const int bn = blockIdx.x * 256;
    const int mc = blockIdx.y * 128;
    const int tid = threadIdx.x;
    const int wv = tid >> 6, lane = tid & 63;
    const int lo = lane & 15, hi = lane >> 4;
    const int lr = lo, quad = hi;
    const int wn = bn + wv * 64;               // wave's 64-col base

    __shared__ u16 Ct[2][16][264];             // 16.5KB C-tile staging

    short8 bf[4][4];                 // 64 VGPR, invariant across m
    #pragma unroll
    for (int nt = 0; nt < 4; ++nt)
        #pragma unroll
        for (int s = 0; s < 4; ++s)
            bf[nt][s] = *(const short8*)(
                wth + (size_t)(wn + nt * 16 + lo) * DIM_ + s * 32 + hi * 8);

    const bool qk = (bn < 2560);               // block-uniform
    const u16* aA = xh + (size_t)(mc + lo) * DIM_ + hi * 8;
    const int sr = tid >> 4, sc = tid & 15;    // store-phase row/lane

#define G1BODY(AF, IT) do {                                                   \
    f32x4 acc[4] = {};                                                        \
    if (qk) {                                                                 \
        _Pragma("unroll")                                                     \
        for (int s = 0; s < 4; ++s)                                           \
            _Pragma("unroll")                                                 \
            for (int nt = 0; nt < 4; ++nt)                                    \
                acc[nt] = MFMA16(bf[nt][s], AF[s], acc[nt], 0, 0, 0);         \
        const int bufq = (IT) & 1;                                            \
        _Pragma("unroll")                                                     \
        for (int nt = 0; nt < 4; ++nt) {                                      \
            uint2 o;                                                          \
            o.x = pkbf(acc[nt][0], acc[nt][1]);                               \
            o.y = pkbf(acc[nt][2], acc[nt][3]);                               \
            *(uint2*)&Ct[bufq][lr][wv * 64 + nt * 16 + quad * 4] = o;         \
        }                                                                     \
        __syncthreads();                                                      \
        const int row = mc + (IT) * 16 + sr;                                  \
        u16* drow = qkvb + (size_t)row * QB_LD + bn;                          \
        short8 v0 = *(const short8*)&Ct[bufq][sr][sc * 8];                    \
        short8 v1 = *(const short8*)&Ct[bufq][sr][128 + sc * 8];              \
        *(short8*)(drow + sc * 8) = v0;                                       \
        *(short8*)(drow + 128 + sc * 8) = v1;                                 \
    } else {                                                                  \
        _Pragma("unroll")                                                     \
        for (int s = 0; s < 4; ++s)                                           \
            _Pragma("unroll")                                                 \
            for (int nt = 0; nt < 4; ++nt)                                    \
                acc[nt] = MFMA16(AF[s], bf[nt][s], acc[nt], 0, 0, 0);         \
        const int m0 = mc + (IT) * 16 + quad * 4;                             \
        const int bb = m0 >> 11, mseq = m0 & 2047;                            \
        _Pragma("unroll")                                                     \
        for (int nt = 0; nt < 4; ++nt) {                                      \
            const int ncol = wn + nt * 16 + lr - 2560;                        \
            const int kvh = ncol >> 7, d = ncol & 127;                        \
            uint2 o;                                                          \
            o.x = pkbf(acc[nt][0], acc[nt][1]);                               \
            o.y = pkbf(acc[nt][2], acc[nt][3]);                               \
            *(uint2*)(vg + ((size_t)(bb * KVH_ + kvh) * DIM_ + d) * VG_LD     \
                      + mseq) = o;                                            \
        }                                                                     \
    }                                                                         \
} while (0)

    short8 afA[4], afB[4];
    #pragma unroll
    for (int s = 0; s < 4; ++s) afA[s] = *(const short8*)(aA + s * 32);

    #pragma unroll 1
    for (int it = 0; it < 8; it += 2) {
        const u16* aN = aA + (size_t)(it + 1) * 16 * DIM_;
        #pragma unroll
        for (int s = 0; s < 4; ++s) afB[s] = *(const short8*)(aN + s * 32);
        G1BODY(afA, it);
        const int nx = (it + 2 < 8) ? (it + 2) : 7;
        const u16* aN2 = aA + (size_t)nx * 16 * DIM_;
        #pragma unroll
        for (int s = 0; s < 4; ++s) afA[s] = *(const short8*)(aN2 + s * 32);
        G1BODY(afB, it + 1);
    }
#undef G1BODY
}

// ---------- Attention v8: 64-key chunks + cross-pipe interleaved round -----
// R13 counters: MfmaUtil 19 + VALU 33 = 52% issue; per-round pipe demand
// (DS 1536 + MFMA 614 + VALU 1040 cyc/SIMD) ~= measured round time -> pipes
// run at SUM not MAX: zero cross-pipe overlap (phase-ordered program + 8
// setprio fences + barrier convoy). v8 interleaves within the round:
// QK burst (16 MFMA) -> SM(0,1) -> pa0 -> SM(2) -> PV[pa0,nt0-3] -> SM(3)
// -> PV[pa0,nt4-7] -> pa1 -> PV[pa1]. PV(pa0) is independent of SM(2/3),
// so softmax VALU hides under PV's DS+MFMA. setprio fences removed.
// c[4] live costs +12 VGPR: ~75 arch + 32 AGPR < 128 -> 4 waves/SIMD kept.
__global__ __launch_bounds__(512) void attn_mfma(
    const u16* __restrict__ qkvb, const u16* __restrict__ vg,
    u16* __restrict__ ah)
{
    const int xcd  = blockIdx.x & 7;
    const int idx  = blockIdx.x >> 3;          // 0..127 per XCD residue
    const int pair = xcd + 8 * (idx & 1);      // 0..15
    const int qt   = idx >> 1;                 // 0..63
    const int b    = pair >> 2, kvh = pair & 3;
    const int q0 = qt << 5;
    const int tid = threadIdx.x;
    const int wv8 = tid >> 6, lane = tid & 63;
    const int hq = wv8 >> 1, mrow = wv8 & 1;   // head-sub, m-half
    const int lr = lane & 15, quad = lane >> 4;
    const int h = kvh * 4 + hq;
    const bool oddq = (quad & 1) != 0;

    __shared__ u16 Kb[2][16][512];   // 32KB  p = g*4+s (g=key16-grp, s=d-slice)
    __shared__ u16 Vb[2][16][512];   // 32KB  p = nt*2+kh (nt=d-blk, kh=key32-half)

    const float scale2 = 0.08838834764831845f * 1.4426950408889634f;
    const float slope2 = exp2f(-0.5f * (float)(h + 1)) * 1.4426950408889634f;
    const int jbase = max(0, q0 - WIN_);
    const int nch = (q0 + 32 - jbase + 63) >> 6;   // 1..9  (64-key chunks)
    const size_t rowb = (size_t)b * SEQ_;
    const u16* kgp = qkvb + rowb * QB_LD + (QH_ + kvh) * DIM_;
    const u16* vgb = vg + (size_t)(b * KVH_ + kvh) * DIM_ * VG_LD;
    const int lo = lane & 15, hi = lane >> 4;

    short8 qf[4];                    // 16 VGPR: this wave's 16 q-rows
    {
        const u16* qp = qkvb + (rowb + q0 + mrow * 16 + lr) * QB_LD
                        + h * DIM_ + quad * 8;
        #pragma unroll
        for (int s = 0; s < 4; ++s) qf[s] = *(const short8*)(qp + 32 * s);
    }

    float alpha0;
    {
        const int q = q0 + mrow * 16 + lr;
        const int rm = (q < WIN_) ? q : WIN_;
        alpha0 = slope2 * (float)(q - rm);
    }

    f32x4 O[8] = {};                 // 32 AGPR: O^T, regs = d, lane col = q
    float rs = 0.f;

    #define STAGE(CH, SLOT) do {                                              \
        const int _jk = jbase + ((CH) << 6);                                  \
        _Pragma("unroll")                                                     \
        for (int _t = 0; _t < 2; ++_t) {                                      \
            const int _p = wv8 + _t * 8;                                      \
            int _kr = _jk + (_p >> 2) * 16 + lo;                              \
            _kr = (_kr < SEQ_) ? _kr : (SEQ_ - 1);                            \
            gload_lds16(kgp + (size_t)_kr * QB_LD + (_p & 3) * 32 + hi * 8,   \
                        &Kb[(SLOT)][_p][0]);                                  \
            int _kc = _jk + (_p & 1) * 32 + hi * 8;                           \
            _kc = (_kc < SEQ_ - 8) ? _kc : (SEQ_ - 8);                        \
            gload_lds16(vgb + (size_t)((_p >> 1) * 16 + lo) * VG_LD + _kc,    \
                        &Vb[(SLOT)][_p][0]);                                  \
        }                                                                     \
    } while (0)

    // Softmax for one 16-key group NT: c[NT] -> pw[NT], rs accumulate.
    #define SM(NT) do {                                                       \
        const int jknt = jk + (NT) * 16;                                      \
        const float b0 = fmaf(-slope2, (float)(jknt + quad * 4), alpha0);     \
        float e0, e1, e2, e3;                                                 \
        if (qm0 >= jknt + 15 && qm0 + 15 <= jknt + WIN_) {                    \
            e0 = EXP2F(fmaf(c[NT][0], scale2, b0));                           \
            e1 = EXP2F(fmaf(c[NT][1], scale2, b0 - slope2));                  \
            e2 = EXP2F(fmaf(c[NT][2], scale2, b0 - 2.f * slope2));            \
            e3 = EXP2F(fmaf(c[NT][3], scale2, b0 - 3.f * slope2));            \
        } else {                                                              \
            const int q = qm0 + lr, j0q = jknt + quad * 4;                    \
            float ee[4];                                                      \
            _Pragma("unroll")                                                 \
            for (int r = 0; r < 4; ++r) {                                     \
                const int rel = q - (j0q + r);                                \
                const float t = fmaf(c[NT][r], scale2,                        \
                                     b0 - (float)r * slope2);                 \
                ee[r] = ((unsigned)rel <= (unsigned)WIN_) ? EXP2F(t) : 0.f;   \
            }                                                                 \
            e0 = ee[0]; e1 = ee[1]; e2 = ee[2]; e3 = ee[3];                   \
        }                                                                     \
        rs += (e0 + e1) + (e2 + e3);                                          \
        pw[NT][0] = pkbf(e0, e1);                                             \
        pw[NT][1] = pkbf(e2, e3);                                             \
    } while (0)

    // In-register P^T redistribution for one 32-key half (R4 algebra).
    #define REDIST(G, PA) do {                                                \
        union { u32 w[4]; short8 s; } P;                                      \
        _Pragma("unroll")                                                     \
        for (int w = 0; w < 2; ++w) {                                         \
            auto r = __builtin_amdgcn_permlane32_swap(                        \
                pw[2 * (G)][w], pw[2 * (G) + 1][w], false, false);            \
            const u32 rx = r[0], ry = r[1];                                   \
            const u32 sx = (u32)__shfl_xor((int)rx, 16);                      \
            const u32 sy = (u32)__shfl_xor((int)ry, 16);                      \
            P.w[w]     = oddq ? sy : rx;                                      \
            P.w[2 + w] = oddq ? ry : sx;                                      \
        }                                                                     \
        PA = P.s;                                                             \
    } while (0)

    STAGE(0, 0);

    for (int ch = 0; ch < nch; ++ch) {
        const int jk = jbase + (ch << 6);
        const int slot = ch & 1;
        __asm__ volatile("s_waitcnt vmcnt(0)" ::: "memory");
        __asm__ volatile("s_barrier" ::: "memory");   // chunk ch staged; slot^1 free
        if (ch + 1 < nch) STAGE(ch + 1, slot ^ 1);

        const int qm0 = q0 + mrow * 16;
        u32 pw[4][2];

        // QK burst: 16 independent MFMA (4 accumulators).
        f32x4 c[4] = {};
        #pragma unroll
        for (int s = 0; s < 4; ++s)
            #pragma unroll
            for (int nt = 0; nt < 4; ++nt) {
                short8 kf = *(const short8*)&Kb[slot][nt * 4 + s][lane * 8];
                c[nt] = MFMA16(kf, qf[s], c[nt], 0, 0, 0);
            }

        short8 pa0, pa1;
        SM(0);
        SM(1);
        REDIST(0, pa0);
        SM(2);                                  // VALU hides under PV below
        #pragma unroll
        for (int nt = 0; nt < 4; ++nt) {
            short8 vf = *(const short8*)&Vb[slot][nt * 2][lane * 8];
            O[nt] = MFMA16(vf, pa0, O[nt], 0, 0, 0);
        }
        SM(3);
        #pragma unroll
        for (int nt = 4; nt < 8; ++nt) {
            short8 vf = *(const short8*)&Vb[slot][nt * 2][lane * 8];
            O[nt] = MFMA16(vf, pa0, O[nt], 0, 0, 0);
        }
        REDIST(1, pa1);
        #pragma unroll
        for (int nt = 0; nt < 8; ++nt) {
            short8 vf = *(const short8*)&Vb[slot][nt * 2 + 1][lane * 8];
            O[nt] = MFMA16(vf, pa1, O[nt], 0, 0, 0);
        }
    }
    #undef STAGE
    #undef SM
    #undef REDIST

    __asm__ volatile("s_waitcnt vmcnt(0)" ::: "memory");

    rs += __shfl_xor(rs, 16);
    rs += __shfl_xor(rs, 32);

    {
        const float inv = 1.0f / rs;
        u16* dst = ah + (rowb + q0 + mrow * 16 + lr) * (size_t)AH_LD
                   + h * DIM_;
        #pragma unroll
        for (int nt = 0; nt < 8; ++nt) {
            uint2 o;
            o.x = pkbf(O[nt][0] * inv, O[nt][1] * inv);
            o.y = pkbf(O[nt][2] * inv, O[nt][3] * inv);
            *(uint2*)(dst + nt * 16 + quad * 4) = o;
        }
    }
}

// ---------- GEMM2 v4: contiguous A-staging (unchanged from R10) ------------
__global__ __launch_bounds__(512) void gemm2_mfma(
    const u16* __restrict__ ah, const u16* __restrict__ wpth,
    float* __restrict__ out)
{
    const int bm = blockIdx.x * 32;            // 256 blocks
    const int tid = threadIdx.x;
    const int wv8 = tid >> 6, lane = tid & 63;
    const int wr = wv8 >> 2, wc = wv8 & 3;     // 2 x 4 wave grid
    const int lr = lane & 15, quad = lane >> 4;

    __shared__ u16 At2[2][32][520];            // 66.5KB

    #define G2STAGE(KS, SLOT) do {                                            \
        _Pragma("unroll")                                                     \
        for (int _t = 0; _t < 4; ++_t) {                                      \
            const int _r = wv8 * 4 + _t;                                      \
            gload_lds16(ah + (size_t)(bm + _r) * AH_LD + (KS) * 512           \
                        + lane * 8, &At2[(SLOT)][_r][0]);                     \
        }                                                                     \
    } while (0)

    f32x4 acc[2] = {};                         // nt = 0,1 (32 cols)

    G2STAGE(0, 0);

    #pragma unroll 1
    for (int ks = 0; ks < 4; ++ks) {
        const int slot = ks & 1;
        __asm__ volatile("s_waitcnt vmcnt(0)" ::: "memory");
        __asm__ volatile("s_barrier" ::: "memory");  // stage(ks) done everywhere
        if (ks < 3) G2STAGE(ks + 1, slot ^ 1);       // slot^1 free (ks-1 done)

        const u16* wbase = wpth + (size_t)(wc * 32 + lr) * WP_LD
                           + ks * 512 + quad * 8;
        #pragma unroll
        for (int s = 0; s < 16; ++s) {
            short8 wf0 = *(const short8*)(wbase + s * 32);
            short8 wf1 = *(const short8*)(wbase + (size_t)16 * WP_LD + s * 32);
            short8 af  = *(const short8*)
                &At2[slot][wr * 16 + lr][s * 32 + quad * 8];
            acc[0] = MFMA16(wf0, af, acc[0], 0, 0, 0);
            acc[1] = MFMA16(wf1, af, acc[1], 0, 0, 0);
        }
    }
    #undef G2STAGE

    __asm__ volatile("s_waitcnt vmcnt(0)" ::: "memory");

    #pragma unroll
    for (int nt = 0; nt < 2; ++nt) {
        float* orow = out + (size_t)(bm + wr * 16 + lr) * DIM_
                      + wc * 32 + nt * 16 + quad * 4;
        *(float4*)orow = *(float4*)&acc[nt];
    }
}

// ---------- launch ----------------------------------------------------------
extern "C" void kernel_launch(void* const* d_in, const int* in_sizes, int n_in,
                              void* d_out, int out_size, void* d_ws, size_t ws_size,
                              hipStream_t stream)
{
    const float* x     = (const float*)d_in[0];
    const float* Wqkv  = (const float*)d_in[1];
    const float* Wproj = (const float*)d_in[2];
    float* out = (float*)d_out;

    u16* xh   = (u16*)d_ws;
    u16* wth  = xh   + (size_t)NX;
    u16* wpth = wth  + (size_t)NWQ;
    u16* qkvb = wpth + (size_t)DIM_ * WP_LD;                 // 128*2112
    u16* vg   = qkvb + (size_t)8192 * QB_LD;                 // 8192*3136
    u16* ahp  = vg   + (size_t)BATCH_ * KVH_ * DIM_ * VG_LD; // 16*128*2112

    prep<<<1024 + 640, 256, 0, stream>>>(x, Wqkv, Wproj, xh, wth, wpth);

    gemm1_mfma<<<dim3(12, 64), 256, 0, stream>>>(xh, wth, qkvb, vg);

    attn_mfma<<<1024, 512, 0, stream>>>(qkvb, vg, ahp);

    gemm2_mfma<<<8192 / 32, 512, 0, stream>>>(ahp, wpth, out);
}

// Round 15
// 178.631 us; speedup vs baseline: 1.1735x; 1.1735x over previous
//
#include <hip/hip_runtime.h>
#include <math.h>

#define DIM_    128
#define QH_     16
#define KVH_    4
#define WIN_    512
#define BATCH_  4
#define SEQ_    2048
#define QKV_LD  3072

// Padded workspace strides (kept from R9 — harmless).
#define QB_LD   3136   // qkvb rows (logical 3072)
#define VG_LD   2112   // vg rows   (logical 2048)
#define AH_LD   2112   // ah rows   (logical 2048)
#define WP_LD   2112   // wpth rows (logical 2048)

#define NX   (BATCH_*SEQ_*DIM_)   // 1048576
#define NWQ  (DIM_*QKV_LD)        // 393216

typedef __attribute__((ext_vector_type(8))) short short8;
typedef __attribute__((ext_vector_type(4))) float f32x4;
typedef unsigned short u16;
typedef unsigned int u32;

__device__ __forceinline__ u16 f2bf(float f) {
    u32 u = __float_as_uint(f);
    u += 0x7fff + ((u >> 16) & 1);
    return (u16)(u >> 16);
}
__device__ __forceinline__ float bf2f(u16 u) {
    return __uint_as_float(((u32)u) << 16);
}
// pack 2 f32 -> 2 bf16 (RNE), single VALU instr (no builtin on gfx950)
__device__ __forceinline__ u32 pkbf(float a, float b) {
    u32 r;
    __asm__("v_cvt_pk_bf16_f32 %0, %1, %2" : "=v"(r) : "v"(a), "v"(b));
    return r;
}
#define MFMA16 __builtin_amdgcn_mfma_f32_16x16x32_bf16

#if __has_builtin(__builtin_amdgcn_exp2f)
#define EXP2F __builtin_amdgcn_exp2f
#else
#define EXP2F exp2f
#endif

__device__ __forceinline__ void gload_lds16(const u16* g, u16* l) {
    __builtin_amdgcn_global_load_lds(
        (const __attribute__((address_space(1))) unsigned int*)(const void*)g,
        (__attribute__((address_space(3))) unsigned int*)(void*)l, 16, 0, 0);
}

// ---------- prep: xcvt + wtrans fused (unchanged) --------------------------
__global__ __launch_bounds__(256) void prep(
    const float* __restrict__ x, const float* __restrict__ Wqkv,
    const float* __restrict__ Wproj,
    u16* __restrict__ xh, u16* __restrict__ wth, u16* __restrict__ wpth)
{
    if (blockIdx.x < 1024) {
        const size_t t = (size_t)blockIdx.x * 256 + threadIdx.x;
        float4 v = *(const float4*)(x + 4 * t);
        ushort4 o;
        o.x = f2bf(v.x); o.y = f2bf(v.y); o.z = f2bf(v.z); o.w = f2bf(v.w);
        *(ushort4*)(xh + 4 * t) = o;
        return;
    }
    __shared__ float T[32][33];
    int tile = blockIdx.x - 1024;
    const float* src; u16* dst; int N, ldo;
    if (tile < 384) { src = Wqkv;  dst = wth;  N = 3072; ldo = 128; }
    else { tile -= 384; src = Wproj; dst = wpth; N = 128; ldo = WP_LD; }
    const int ntile = N >> 5;
    const int k0 = (tile / ntile) << 5, n0 = (tile % ntile) << 5;
    const int tx = threadIdx.x & 31, ty = threadIdx.x >> 5;
    #pragma unroll
    for (int i = 0; i < 4; ++i)
        T[ty + 8 * i][tx] = src[(size_t)(k0 + ty + 8 * i) * N + n0 + tx];
    __syncthreads();
    #pragma unroll
    for (int i = 0; i < 4; ++i)
        dst[(size_t)(n0 + ty + 8 * i) * ldo + k0 + tx] = f2bf(T[tx][ty + 8 * i]);
}

// ---------- GEMM1 v4: LDS-staged store epilogue (unchanged from R12) -------
__global__ __launch_bounds__(256) void gemm1_mfma(
    const u16* __restrict__ xh, const u16* __restrict__ wth,
    u16* __restrict__ qkvb, u16* __restrict__ vg)
{
    const int bn = blockIdx.x * 256;
    const int mc = blockIdx.y * 128;
    const int tid = threadIdx.x;
    const int wv = tid >> 6, lane = tid & 63;
    const int lo = lane & 15, hi = lane >> 4;
    const int lr = lo, quad = hi;
    const int wn = bn + wv * 64;               // wave's 64-col base

    __shared__ u16 Ct[2][16][264];             // 16.5KB C-tile staging

    short8 bf[4][4];                 // 64 VGPR, invariant across m
    #pragma unroll
    for (int nt = 0; nt < 4; ++nt)
        #pragma unroll
        for (int s = 0; s < 4; ++s)
            bf[nt][s] = *(const short8*)(
                wth + (size_t)(wn + nt * 16 + lo) * DIM_ + s * 32 + hi * 8);

    const bool qk = (bn < 2560);               // block-uniform
    const u16* aA = xh + (size_t)(mc + lo) * DIM_ + hi * 8;
    const int sr = tid >> 4, sc = tid & 15;    // store-phase row/lane

#define G1BODY(AF, IT) do {                                                   \
    f32x4 acc[4] = {};                                                        \
    if (qk) {                                                                 \
        _Pragma("unroll")                                                     \
        for (int s = 0; s < 4; ++s)                                           \
            _Pragma("unroll")                                                 \
            for (int nt = 0; nt < 4; ++nt)                                    \
                acc[nt] = MFMA16(bf[nt][s], AF[s], acc[nt], 0, 0, 0);         \
        const int bufq = (IT) & 1;                                            \
        _Pragma("unroll")                                                     \
        for (int nt = 0; nt < 4; ++nt) {                                      \
            uint2 o;                                                          \
            o.x = pkbf(acc[nt][0], acc[nt][1]);                               \
            o.y = pkbf(acc[nt][2], acc[nt][3]);                               \
            *(uint2*)&Ct[bufq][lr][wv * 64 + nt * 16 + quad * 4] = o;         \
        }                                                                     \
        __syncthreads();                                                      \
        const int row = mc + (IT) * 16 + sr;                                  \
        u16* drow = qkvb + (size_t)row * QB_LD + bn;                          \
        short8 v0 = *(const short8*)&Ct[bufq][sr][sc * 8];                    \
        short8 v1 = *(const short8*)&Ct[bufq][sr][128 + sc * 8];              \
        *(short8*)(drow + sc * 8) = v0;                                       \
        *(short8*)(drow + 128 + sc * 8) = v1;                                 \
    } else {                                                                  \
        _Pragma("unroll")                                                     \
        for (int s = 0; s < 4; ++s)                                           \
            _Pragma("unroll")                                                 \
            for (int nt = 0; nt < 4; ++nt)                                    \
                acc[nt] = MFMA16(AF[s], bf[nt][s], acc[nt], 0, 0, 0);         \
        const int m0 = mc + (IT) * 16 + quad * 4;                             \
        const int bb = m0 >> 11, mseq = m0 & 2047;                            \
        _Pragma("unroll")                                                     \
        for (int nt = 0; nt < 4; ++nt) {                                      \
            const int ncol = wn + nt * 16 + lr - 2560;                        \
            const int kvh = ncol >> 7, d = ncol & 127;                        \
            uint2 o;                                                          \
            o.x = pkbf(acc[nt][0], acc[nt][1]);                               \
            o.y = pkbf(acc[nt][2], acc[nt][3]);                               \
            *(uint2*)(vg + ((size_t)(bb * KVH_ + kvh) * DIM_ + d) * VG_LD     \
                      + mseq) = o;                                            \
        }                                                                     \
    }                                                                         \
} while (0)

    short8 afA[4], afB[4];
    #pragma unroll
    for (int s = 0; s < 4; ++s) afA[s] = *(const short8*)(aA + s * 32);

    #pragma unroll 1
    for (int it = 0; it < 8; it += 2) {
        const u16* aN = aA + (size_t)(it + 1) * 16 * DIM_;
        #pragma unroll
        for (int s = 0; s < 4; ++s) afB[s] = *(const short8*)(aN + s * 32);
        G1BODY(afA, it);
        const int nx = (it + 2 < 8) ? (it + 2) : 7;
        const u16* aN2 = aA + (size_t)nx * 16 * DIM_;
        #pragma unroll
        for (int s = 0; s < 4; ++s) afA[s] = *(const short8*)(aN2 + s * 32);
        G1BODY(afB, it + 1);
    }
#undef G1BODY
}

// ---------- Attention v7 (R13 verbatim): 64-key chunks, 2-slot ring --------
// R14's hand-interleave regressed (98us, occ 20%): register pressure +
// order-pinning beat the compiler's schedule. Reverted to the proven v7.
__global__ __launch_bounds__(512) void attn_mfma(
    const u16* __restrict__ qkvb, const u16* __restrict__ vg,
    u16* __restrict__ ah)
{
    const int xcd  = blockIdx.x & 7;
    const int idx  = blockIdx.x >> 3;          // 0..127 per XCD residue
    const int pair = xcd + 8 * (idx & 1);      // 0..15
    const int qt   = idx >> 1;                 // 0..63
    const int b    = pair >> 2, kvh = pair & 3;
    const int q0 = qt << 5;
    const int tid = threadIdx.x;
    const int wv8 = tid >> 6, lane = tid & 63;
    const int hq = wv8 >> 1, mrow = wv8 & 1;   // head-sub, m-half
    const int lr = lane & 15, quad = lane >> 4;
    const int h = kvh * 4 + hq;
    const bool oddq = (quad & 1) != 0;

    __shared__ u16 Kb[2][16][512];   // 32KB  p = g*4+s (g=key16-grp, s=d-slice)
    __shared__ u16 Vb[2][16][512];   // 32KB  p = nt*2+kh (nt=d-blk, kh=key32-half)

    const float scale2 = 0.08838834764831845f * 1.4426950408889634f;
    const float slope2 = exp2f(-0.5f * (float)(h + 1)) * 1.4426950408889634f;
    const int jbase = max(0, q0 - WIN_);
    const int nch = (q0 + 32 - jbase + 63) >> 6;   // 1..9  (64-key chunks)
    const size_t rowb = (size_t)b * SEQ_;
    const u16* kgp = qkvb + rowb * QB_LD + (QH_ + kvh) * DIM_;
    const u16* vgb = vg + (size_t)(b * KVH_ + kvh) * DIM_ * VG_LD;
    const int lo = lane & 15, hi = lane >> 4;

    short8 qf[4];                    // 16 VGPR: this wave's 16 q-rows
    {
        const u16* qp = qkvb + (rowb + q0 + mrow * 16 + lr) * QB_LD
                        + h * DIM_ + quad * 8;
        #pragma unroll
        for (int s = 0; s < 4; ++s) qf[s] = *(const short8*)(qp + 32 * s);
    }

    float alpha0;
    {
        const int q = q0 + mrow * 16 + lr;
        const int rm = (q < WIN_) ? q : WIN_;
        alpha0 = slope2 * (float)(q - rm);
    }

    f32x4 O[8] = {};                 // 32 AGPR: O^T, regs = d, lane col = q
    float rs = 0.f;

    #define STAGE(CH, SLOT) do {                                              \
        const int _jk = jbase + ((CH) << 6);                                  \
        _Pragma("unroll")                                                     \
        for (int _t = 0; _t < 2; ++_t) {                                      \
            const int _p = wv8 + _t * 8;                                      \
            int _kr = _jk + (_p >> 2) * 16 + lo;                              \
            _kr = (_kr < SEQ_) ? _kr : (SEQ_ - 1);                            \
            gload_lds16(kgp + (size_t)_kr * QB_LD + (_p & 3) * 32 + hi * 8,   \
                        &Kb[(SLOT)][_p][0]);                                  \
            int _kc = _jk + (_p & 1) * 32 + hi * 8;                           \
            _kc = (_kc < SEQ_ - 8) ? _kc : (SEQ_ - 8);                        \
            gload_lds16(vgb + (size_t)((_p >> 1) * 16 + lo) * VG_LD + _kc,    \
                        &Vb[(SLOT)][_p][0]);                                  \
        }                                                                     \
    } while (0)

    STAGE(0, 0);

    for (int ch = 0; ch < nch; ++ch) {
        const int jk = jbase + (ch << 6);
        const int slot = ch & 1;
        __asm__ volatile("s_waitcnt vmcnt(0)" ::: "memory");
        __asm__ volatile("s_barrier" ::: "memory");   // chunk ch staged; slot^1 free
        if (ch + 1 < nch) STAGE(ch + 1, slot ^ 1);

        u32 pw[4][2];                // [nt16][w] packed bf16 pairs
        const int qm0 = q0 + mrow * 16;
        #pragma unroll
        for (int nt = 0; nt < 4; ++nt) {
            f32x4 c = {0.f, 0.f, 0.f, 0.f};
            __builtin_amdgcn_s_setprio(1);
            #pragma unroll
            for (int s = 0; s < 4; ++s) {
                short8 kf = *(const short8*)&Kb[slot][nt * 4 + s][lane * 8];
                c = MFMA16(kf, qf[s], c, 0, 0, 0);
            }
            __builtin_amdgcn_s_setprio(0);
            const int jknt = jk + nt * 16;
            const float b0 = fmaf(-slope2, (float)(jknt + quad * 4), alpha0);
            float e0, e1, e2, e3;
            if (qm0 >= jknt + 15 && qm0 + 15 <= jknt + WIN_) {   // full
                e0 = EXP2F(fmaf(c[0], scale2, b0));
                e1 = EXP2F(fmaf(c[1], scale2, b0 - slope2));
                e2 = EXP2F(fmaf(c[2], scale2, b0 - 2.f * slope2));
                e3 = EXP2F(fmaf(c[3], scale2, b0 - 3.f * slope2));
            } else {                                              // edge
                const int q = qm0 + lr, j0q = jknt + quad * 4;
                float ee[4];
                #pragma unroll
                for (int r = 0; r < 4; ++r) {
                    const int rel = q - (j0q + r);
                    const float t = fmaf(c[r], scale2, b0 - (float)r * slope2);
                    ee[r] = ((unsigned)rel <= (unsigned)WIN_) ? EXP2F(t) : 0.f;
                }
                e0 = ee[0]; e1 = ee[1]; e2 = ee[2]; e3 = ee[3];
            }
            rs += (e0 + e1) + (e2 + e3);
            pw[nt][0] = pkbf(e0, e1);
            pw[nt][1] = pkbf(e2, e3);
        }

        // In-register P^T redistribution, one per 32-key half (R4 algebra).
        short8 pa[2];
        #pragma unroll
        for (int g = 0; g < 2; ++g) {
            union { u32 w[4]; short8 s; } P;
            #pragma unroll
            for (int w = 0; w < 2; ++w) {
                auto r = __builtin_amdgcn_permlane32_swap(
                    pw[2 * g][w], pw[2 * g + 1][w], false, false);
                const u32 rx = r[0], ry = r[1];
                const u32 sx = (u32)__shfl_xor((int)rx, 16);
                const u32 sy = (u32)__shfl_xor((int)ry, 16);
                P.w[w]     = oddq ? sy : rx;
                P.w[2 + w] = oddq ? ry : sx;
            }
            pa[g] = P.s;
        }

        __builtin_amdgcn_s_setprio(1);
        #pragma unroll
        for (int nt = 0; nt < 8; ++nt) {
            short8 vf0 = *(const short8*)&Vb[slot][nt * 2][lane * 8];
            short8 vf1 = *(const short8*)&Vb[slot][nt * 2 + 1][lane * 8];
            O[nt] = MFMA16(vf0, pa[0], O[nt], 0, 0, 0);
            O[nt] = MFMA16(vf1, pa[1], O[nt], 0, 0, 0);
        }
        __builtin_amdgcn_s_setprio(0);
    }
    #undef STAGE

    __asm__ volatile("s_waitcnt vmcnt(0)" ::: "memory");

    rs += __shfl_xor(rs, 16);
    rs += __shfl_xor(rs, 32);

    {
        const float inv = 1.0f / rs;
        u16* dst = ah + (rowb + q0 + mrow * 16 + lr) * (size_t)AH_LD
                   + h * DIM_;
        #pragma unroll
        for (int nt = 0; nt < 8; ++nt) {
            uint2 o;
            o.x = pkbf(O[nt][0] * inv, O[nt][1] * inv);
            o.y = pkbf(O[nt][2] * inv, O[nt][3] * inv);
            *(uint2*)(dst + nt * 16 + quad * 4) = o;
        }
    }
}

// ---------- GEMM2 v5: 16-row blocks, 2 blocks/CU for cross-block overlap ---
// v4 ran at 1 block/CU (grid 256, LDS 66.5KB): during each megastep's
// vmcnt(0) drain + W L2-latency, the SIMD (2 waves) had nothing to run.
// v5: 16 rows/block -> 512 blocks = 2 blocks/CU (LDS 33.3KB, 4-block
// headroom). Wave = 16r x 16c (acc = 4 AGPR, tiny VGPR): one block's
// compute hides the other's stage drain. W traffic 256MB L2 (~7us BW, ok).
__global__ __launch_bounds__(512) void gemm2_mfma(
    const u16* __restrict__ ah, const u16* __restrict__ wpth,
    float* __restrict__ out)
{
    const int bm = blockIdx.x * 16;            // 512 blocks
    const int tid = threadIdx.x;
    const int wv8 = tid >> 6, lane = tid & 63;
    const int wc = wv8;                        // wave col-group (16 cols)
    const int lr = lane & 15, quad = lane >> 4;

    __shared__ u16 At2[2][16][520];            // 33.3KB

    // 2 contiguous 1KB row-chunk loads per wave per megastep.
    #define G2STAGE(KS, SLOT) do {                                            \
        _Pragma("unroll")                                                     \
        for (int _t = 0; _t < 2; ++_t) {                                      \
            const int _r = wv8 * 2 + _t;                                      \
            gload_lds16(ah + (size_t)(bm + _r) * AH_LD + (KS) * 512           \
                        + lane * 8, &At2[(SLOT)][_r][0]);                     \
        }                                                                     \
    } while (0)

    f32x4 acc = {0.f, 0.f, 0.f, 0.f};

    G2STAGE(0, 0);

    #pragma unroll 1
    for (int ks = 0; ks < 4; ++ks) {
        const int slot = ks & 1;
        __asm__ volatile("s_waitcnt vmcnt(0)" ::: "memory");
        __asm__ volatile("s_barrier" ::: "memory");  // stage(ks) done everywhere
        if (ks < 3) G2STAGE(ks + 1, slot ^ 1);       // slot^1 free (ks-1 done)

        const u16* wbase = wpth + (size_t)(wc * 16 + lr) * WP_LD
                           + ks * 512 + quad * 8;
        #pragma unroll
        for (int s = 0; s < 16; ++s) {
            short8 wf = *(const short8*)(wbase + s * 32);
            short8 af = *(const short8*)&At2[slot][lr][s * 32 + quad * 8];
            acc = MFMA16(wf, af, acc, 0, 0, 0);
        }
    }
    #undef G2STAGE

    __asm__ volatile("s_waitcnt vmcnt(0)" ::: "memory");

    {
        float* orow = out + (size_t)(bm + lr) * DIM_ + wc * 16 + quad * 4;
        *(float4*)orow = *(float4*)&acc;
    }
}

// ---------- launch ----------------------------------------------------------
extern "C" void kernel_launch(void* const* d_in, const int* in_sizes, int n_in,
                              void* d_out, int out_size, void* d_ws, size_t ws_size,
                              hipStream_t stream)
{
    const float* x     = (const float*)d_in[0];
    const float* Wqkv  = (const float*)d_in[1];
    const float* Wproj = (const float*)d_in[2];
    float* out = (float*)d_out;

    u16* xh   = (u16*)d_ws;
    u16* wth  = xh   + (size_t)NX;
    u16* wpth = wth  + (size_t)NWQ;
    u16* qkvb = wpth + (size_t)DIM_ * WP_LD;                 // 128*2112
    u16* vg   = qkvb + (size_t)8192 * QB_LD;                 // 8192*3136
    u16* ahp  = vg   + (size_t)BATCH_ * KVH_ * DIM_ * VG_LD; // 16*128*2112

    prep<<<1024 + 640, 256, 0, stream>>>(x, Wqkv, Wproj, xh, wth, wpth);

    gemm1_mfma<<<dim3(12, 64), 256, 0, stream>>>(xh, wth, qkvb, vg);

    attn_mfma<<<1024, 512, 0, stream>>>(qkvb, vg, ahp);

    gemm2_mfma<<<8192 / 16, 512, 0, stream>>>(ahp, wpth, out);
}